// Round 7
// baseline (284.427 us; speedup 1.0000x reference)
//
#include <hip/hip_runtime.h>

// SparsePropMaxPool — R7 TIMING PROBE (deliberate, correctness-preserving
// regression): R6 kernel + a SECOND identical store pass over map_h.
// Purpose: measure the marginal cost of one full 268 MB write pass in
// compute-kernel context. After 4 falsified theories (NT/L2-policy, channel
// camping, segment scatter, occupancy), the two live models are:
//   (a) compute-kernel writes drain at ~3 TB/s -> delta ~ +90 us
//   (b) kernel already at ~45-50 us write floor; residual is harness
//       reset()'s dozens of tiny dispatches -> delta ~ +45-55 us
// The asm memory clobber between passes prevents dead-store elimination
// of pass 1. Values are identical in both passes -> output unchanged.

#define BB 32
#define HH 512
#define NN 64

typedef float f32x4 __attribute__((ext_vector_type(4)));

__device__ __forceinline__ unsigned long long active_mask_for_e(int e) {
    unsigned long long m;
    if (e >= 15) m = 0xFFFFull << (e - 15);
    else         m = 0xFFFFull >> (15 - e);
    if ((e & 1) && e >= 17) {
        int a = e - 31; if (a < 0) a = 0;
        int b = e - 17;
        unsigned long long r = (~0ull >> (63 - b)) & (~0ull << a);
        m |= r & 0x5555555555555555ull;
    }
    if (((e & 3) == 3) && e >= 35) {
        int b = e - 35;
        unsigned long long r = (~0ull >> (63 - b));
        m |= r & 0x1111111111111111ull;
    }
    return m;
}

__global__ __launch_bounds__(256, 8) void sppool_fused_kernel(
        const float* __restrict__ x, float* __restrict__ map_h,
        float* __restrict__ map_mask) {
    __shared__ float sp[4][7][68];

    const int tid  = threadIdx.x;
    const int wv   = tid >> 6;                 // wave 0..3
    const int lane = tid & 63;
    const int row  = blockIdx.x * 4 + wv;      // one row per wave

    // barrier-free build: register recurrence + private LDS slice
    float v = x[(size_t)row * NN + lane];
    sp[wv][0][lane] = v;
    #pragma unroll
    for (int k = 1; k <= 6; ++k) {
        int p = lane + (1 << (k - 1)); if (p > 63) p = 63;
        const float o = __shfl(v, p);
        v = fmaxf(v, o);
        sp[wv][k][lane] = v;
    }
    __builtin_amdgcn_wave_barrier();

    const int sg = lane >> 4;
    const int e0 = (lane & 15) << 2;

    const unsigned long long am0 = active_mask_for_e(e0 + 0);
    const unsigned long long am1 = active_mask_for_e(e0 + 1);
    const unsigned long long am2 = active_mask_for_e(e0 + 2);
    const unsigned long long am3 = active_mask_for_e(e0 + 3);

    const float* rowsp = &sp[wv][0][0];
    float* outr = map_h + (size_t)row * (NN * NN) + e0;

    // ---- PASS 1 ----
    #pragma unroll 4
    for (int t = 0; t < 16; ++t) {
        const int s = (t << 2) + sg;
        f32x4 o;
        #pragma unroll
        for (int j = 0; j < 4; ++j) {
            const int e = e0 + j;
            int n = e - s + 1; if (n < 1) n = 1;
            const int k = 31 - __clz(n);
            const float lo = rowsp[k * 68 + s];
            const float hi = rowsp[k * 68 + (e + 1 - (1 << k))];
            const unsigned long long am = (j == 0) ? am0 : (j == 1) ? am1
                                        : (j == 2) ? am2 : am3;
            o[j] = ((am >> s) & 1ull) ? fmaxf(lo, hi) : 0.0f;
        }
        *reinterpret_cast<f32x4*>(outr + (size_t)s * NN) = o;
    }

    // keep pass-1 stores live; forbid cross-loop dead-store elimination
    asm volatile("" ::: "memory");

    // ---- PASS 2 (identical values, identical addresses) ----
    #pragma unroll 4
    for (int t = 0; t < 16; ++t) {
        const int s = (t << 2) + sg;
        f32x4 o;
        #pragma unroll
        for (int j = 0; j < 4; ++j) {
            const int e = e0 + j;
            int n = e - s + 1; if (n < 1) n = 1;
            const int k = 31 - __clz(n);
            const float lo = rowsp[k * 68 + s];
            const float hi = rowsp[k * 68 + (e + 1 - (1 << k))];
            const unsigned long long am = (j == 0) ? am0 : (j == 1) ? am1
                                        : (j == 2) ? am2 : am3;
            o[j] = ((am >> s) & 1ull) ? fmaxf(lo, hi) : 0.0f;
        }
        *reinterpret_cast<f32x4*>(outr + (size_t)s * NN) = o;
    }

    // fused mask tail (single pass; 0.5 MB, negligible)
    if (blockIdx.x < BB) {
        f32x4* mout = reinterpret_cast<f32x4*>(
            map_mask + (size_t)blockIdx.x * (NN * NN));
        #pragma unroll
        for (int kk = 0; kk < 4; ++kk) {
            const int idx = kk * 256 + tid;
            const int eg  = (idx & 15) << 2;
            const int s   = idx >> 4;
            f32x4 mv;
            mv.x = ((active_mask_for_e(eg + 0) >> s) & 1ull) ? 1.0f : 0.0f;
            mv.y = ((active_mask_for_e(eg + 1) >> s) & 1ull) ? 1.0f : 0.0f;
            mv.z = ((active_mask_for_e(eg + 2) >> s) & 1ull) ? 1.0f : 0.0f;
            mv.w = ((active_mask_for_e(eg + 3) >> s) & 1ull) ? 1.0f : 0.0f;
            mout[idx] = mv;
        }
    }
}

extern "C" void kernel_launch(void* const* d_in, const int* in_sizes, int n_in,
                              void* d_out, int out_size, void* d_ws, size_t ws_size,
                              hipStream_t stream) {
    const float* x = (const float*)d_in[0];
    float* map_h    = (float*)d_out;
    float* map_mask = (float*)d_out + (size_t)BB * HH * NN * NN;

    sppool_fused_kernel<<<BB * HH / 4, 256, 0, stream>>>(x, map_h, map_mask);
}

// Round 8
// 278.009 us; speedup vs baseline: 1.0231x; 1.0231x over previous
//
#include <hip/hip_runtime.h>

// SparsePropMaxPool: map_h[b,h,s,e] = max(x[b,h,s..e]) at active (s,e), else 0;
// map_mask[b,0,s,e] = active ? 1 : 0.  B=32,H=512,N=64.
//
// Active predicate (d = e - s >= 0), from NUM_SCALE_LAYERS=[16,8,8]:
//   scale 0: d in [0,15], any s
//   scale 1: d odd in [17,31], s even
//   scale 2: d%4==3 in [35,63], s%4==0
//
// R8 change: WRITE-STREAM COUNT. Dead theories: NT/L2-policy (R2), channel
// camping (R3), segment scatter (R4), high occupancy (R6); R7 probe pinned
// the first-write drain at ~4.7 TB/s with issue-side <=26us. Remaining
// difference vs the 6.3 TB/s harness fill: the fill runs ~3 waves/CU (~800
// long sequential write streams; Occupancy ~10%), ours ran 16-32 waves/CU
// (4-8k interleaved 16KB streams) -> more streams than HBM banks -> row
// activate per burst -> ~half BW. This kernel matches the fill: 256 blocks
// (1/CU), 4 waves/CU, each wave writes 16 consecutive rows = 256KB fully
// sequential ascending (~1024 streams machine-wide).

#define BB 32
#define HH 512
#define NN 64

typedef float f32x4 __attribute__((ext_vector_type(4)));

__device__ __forceinline__ unsigned long long active_mask_for_e(int e) {
    unsigned long long m;
    if (e >= 15) m = 0xFFFFull << (e - 15);
    else         m = 0xFFFFull >> (15 - e);
    if ((e & 1) && e >= 17) {
        int a = e - 31; if (a < 0) a = 0;
        int b = e - 17;
        unsigned long long r = (~0ull >> (63 - b)) & (~0ull << a);
        m |= r & 0x5555555555555555ull;
    }
    if (((e & 3) == 3) && e >= 35) {
        int b = e - 35;
        unsigned long long r = (~0ull >> (63 - b));
        m |= r & 0x1111111111111111ull;
    }
    return m;
}

__global__ __launch_bounds__(256) void sppool_fused_kernel(
        const float* __restrict__ x, float* __restrict__ map_h,
        float* __restrict__ map_mask) {
    // Per-wave private sparse table, rebuilt per row:
    // sp[wv][k][i] = max(x[row][i .. i+2^k-1]); level stride 68 spreads banks.
    __shared__ float sp[4][7][68];

    const int tid  = threadIdx.x;
    const int wv   = tid >> 6;                 // wave 0..3
    const int lane = tid & 63;

    const int sg = lane >> 4;                  // s sub-line 0..3
    const int e0 = (lane & 15) << 2;           // this lane's 4 e-values

    const unsigned long long am0 = active_mask_for_e(e0 + 0);
    const unsigned long long am1 = active_mask_for_e(e0 + 1);
    const unsigned long long am2 = active_mask_for_e(e0 + 2);
    const unsigned long long am3 = active_mask_for_e(e0 + 3);

    const float* rowsp = &sp[wv][0][0];
    // wave wv of block b owns rows [b*64 + wv*16, +16): 256KB sequential
    const int row0 = blockIdx.x * 64 + wv * 16;

    for (int i = 0; i < 16; ++i) {
        const int row = row0 + i;

        // ---- barrier-free per-wave table build (shfl recurrence) ----
        float v = x[(size_t)row * NN + lane];   // 256B coalesced per wave
        sp[wv][0][lane] = v;
        #pragma unroll
        for (int k = 1; k <= 6; ++k) {
            int p = lane + (1 << (k - 1)); if (p > 63) p = 63;
            const float o = __shfl(v, p);
            v = fmaxf(v, o);
            sp[wv][k][lane] = v;
        }
        __builtin_amdgcn_wave_barrier();        // wave-synchronous LDS: no reorder

        // ---- stream this row's 16KB plane, ascending, 1KB per store instr
        float* outr = map_h + (size_t)row * (NN * NN) + e0;
        #pragma unroll 4
        for (int t = 0; t < 16; ++t) {
            const int s = (t << 2) + sg;
            f32x4 o;
            #pragma unroll
            for (int j = 0; j < 4; ++j) {
                const int e = e0 + j;
                int n = e - s + 1; if (n < 1) n = 1;   // d<0 -> masked anyway
                const int k = 31 - __clz(n);
                const float lo = rowsp[k * 68 + s];
                const float hi = rowsp[k * 68 + (e + 1 - (1 << k))];
                const unsigned long long am = (j == 0) ? am0 : (j == 1) ? am1
                                            : (j == 2) ? am2 : am3;
                o[j] = ((am >> s) & 1ull) ? fmaxf(lo, hi) : 0.0f;
            }
            *reinterpret_cast<f32x4*>(outr + (size_t)s * NN) = o;
        }
        __builtin_amdgcn_wave_barrier();        // table reads done before rebuild
    }

    // Fused mask tail: plane is b-independent; blocks 0..31 emit one each.
    if (blockIdx.x < BB) {
        f32x4* mout = reinterpret_cast<f32x4*>(
            map_mask + (size_t)blockIdx.x * (NN * NN));
        #pragma unroll
        for (int kk = 0; kk < 4; ++kk) {
            const int idx = kk * 256 + tid;     // 1024 float4 per plane
            const int eg  = (idx & 15) << 2;
            const int s   = idx >> 4;
            f32x4 mv;
            mv.x = ((active_mask_for_e(eg + 0) >> s) & 1ull) ? 1.0f : 0.0f;
            mv.y = ((active_mask_for_e(eg + 1) >> s) & 1ull) ? 1.0f : 0.0f;
            mv.z = ((active_mask_for_e(eg + 2) >> s) & 1ull) ? 1.0f : 0.0f;
            mv.w = ((active_mask_for_e(eg + 3) >> s) & 1ull) ? 1.0f : 0.0f;
            mout[idx] = mv;
        }
    }
}

extern "C" void kernel_launch(void* const* d_in, const int* in_sizes, int n_in,
                              void* d_out, int out_size, void* d_ws, size_t ws_size,
                              hipStream_t stream) {
    const float* x = (const float*)d_in[0];
    float* map_h    = (float*)d_out;
    float* map_mask = (float*)d_out + (size_t)BB * HH * NN * NN;

    // 256 blocks (1/CU), 4 waves each, 16 rows per wave = 16384 rows
    sppool_fused_kernel<<<256, 256, 0, stream>>>(x, map_h, map_mask);
}

// Round 9
// 257.908 us; speedup vs baseline: 1.1028x; 1.0779x over previous
//
#include <hip/hip_runtime.h>

// SparsePropMaxPool: map_h[b,h,s,e] = max(x[b,h,s..e]) at "active" (s,e),
// 0 elsewhere; map_mask[b,0,s,e] = active ? 1 : 0.  B=32, H=512, N=64.
//
// Active predicate (d = e - s >= 0), from NUM_SCALE_LAYERS=[16,8,8]:
//   scale 0: d in [0,15], any s
//   scale 1: d odd in [17,31], s even
//   scale 2: d%4==3 in [35,63], s%4==0
//
// R9 = revert to R6 (best verified: 258.1 us @ fill ~170; R0-equivalent).
// Session ledger — mechanisms tested against the ~4.7 TB/s apparent write
// drain, ALL null: NT/L2-bypass (R2), HBM-channel decorrelation (R3),
// 1KB-contiguous per-instr stores (R4), 32 waves/CU (R6), fill-matched
// 4 waves/CU + 256KB sequential streams (R8, regressed: issue-bound).
// R7 double-write probe: +26 us marginal (L2-absorbed -> inconclusive on
// first-write rate). Converged model: map kernel is at/near the 6.3 TB/s
// write ceiling (~43-55 us for 269 MB mandatory writes); the rest of the
// timed loop is harness-fixed (poison fill 165-172 us + reset dispatch
// tail ~35-45 us). Structural floor ~250-260 us == measured.

#define BB 32
#define HH 512
#define NN 64

typedef float f32x4 __attribute__((ext_vector_type(4)));

__device__ __forceinline__ unsigned long long active_mask_for_e(int e) {
    // Bit s set <=> (s, e) is an active position.
    unsigned long long m;
    // band 1: s in [e-15, e]  (d in [0,15])
    if (e >= 15) m = 0xFFFFull << (e - 15);
    else         m = 0xFFFFull >> (15 - e);
    // band 2: d odd in [17,31], s even => only when e is odd
    if ((e & 1) && e >= 17) {
        int a = e - 31; if (a < 0) a = 0;
        int b = e - 17;
        unsigned long long r = (~0ull >> (63 - b)) & (~0ull << a);
        m |= r & 0x5555555555555555ull;
    }
    // band 3: d%4==3 in [35,63], s%4==0 => only when e%4==3
    if (((e & 3) == 3) && e >= 35) {
        int b = e - 35;
        unsigned long long r = (~0ull >> (63 - b));
        m |= r & 0x1111111111111111ull;
    }
    return m;
}

__global__ __launch_bounds__(256, 8) void sppool_fused_kernel(
        const float* __restrict__ x, float* __restrict__ map_h,
        float* __restrict__ map_mask) {
    // Per-wave private sparse table: sp[wv][k][i] = max(x[row][i..i+2^k-1]).
    // Level stride 68 floats (4k mod 32 -> levels spread across banks).
    __shared__ float sp[4][7][68];

    const int tid  = threadIdx.x;
    const int wv   = tid >> 6;                 // wave 0..3
    const int lane = tid & 63;
    const int row  = blockIdx.x * 4 + wv;      // one row per wave

    // ---- barrier-free build: shfl recurrence + private LDS slice ----
    // lane l carries v_k = max(x[row][l .. min(l+2^k-1, 63)])
    float v = x[(size_t)row * NN + lane];       // 256B coalesced per wave
    sp[wv][0][lane] = v;
    #pragma unroll
    for (int k = 1; k <= 6; ++k) {
        int p = lane + (1 << (k - 1)); if (p > 63) p = 63;  // clamped: never queried
        const float o = __shfl(v, p);
        v = fmaxf(v, o);
        sp[wv][k][lane] = v;
    }
    // wave-synchronous LDS: writes precede reads in program order; fence reorder
    __builtin_amdgcn_wave_barrier();

    // ---- main loop: this wave streams its row; 1KB contiguous per instr ----
    const int sg = lane >> 4;                  // s sub-line 0..3
    const int e0 = (lane & 15) << 2;           // this lane's 4 e-values

    const unsigned long long am0 = active_mask_for_e(e0 + 0);
    const unsigned long long am1 = active_mask_for_e(e0 + 1);
    const unsigned long long am2 = active_mask_for_e(e0 + 2);
    const unsigned long long am3 = active_mask_for_e(e0 + 3);

    const float* rowsp = &sp[wv][0][0];
    float* outr = map_h + (size_t)row * (NN * NN) + e0;

    #pragma unroll 4
    for (int t = 0; t < 16; ++t) {
        const int s = (t << 2) + sg;
        f32x4 o;
        #pragma unroll
        for (int j = 0; j < 4; ++j) {
            const int e = e0 + j;
            int n = e - s + 1; if (n < 1) n = 1;   // d<0 -> masked anyway
            const int k = 31 - __clz(n);
            const float lo = rowsp[k * 68 + s];
            const float hi = rowsp[k * 68 + (e + 1 - (1 << k))];
            const unsigned long long am = (j == 0) ? am0 : (j == 1) ? am1
                                        : (j == 2) ? am2 : am3;
            o[j] = ((am >> s) & 1ull) ? fmaxf(lo, hi) : 0.0f;
        }
        // wave: lanes 0..63 cover bytes [4t*256 .. 4t*256+1024) contiguous
        *reinterpret_cast<f32x4*>(outr + (size_t)s * NN) = o;
    }

    // Fused mask tail: the 64x64 mask plane is b-independent; blocks 0..31
    // emit one plane each (16 KB).
    if (blockIdx.x < BB) {
        f32x4* mout = reinterpret_cast<f32x4*>(
            map_mask + (size_t)blockIdx.x * (NN * NN));
        #pragma unroll
        for (int kk = 0; kk < 4; ++kk) {
            const int idx = kk * 256 + tid;    // 1024 float4 per plane
            const int eg  = (idx & 15) << 2;
            const int s   = idx >> 4;
            f32x4 mv;
            mv.x = ((active_mask_for_e(eg + 0) >> s) & 1ull) ? 1.0f : 0.0f;
            mv.y = ((active_mask_for_e(eg + 1) >> s) & 1ull) ? 1.0f : 0.0f;
            mv.z = ((active_mask_for_e(eg + 2) >> s) & 1ull) ? 1.0f : 0.0f;
            mv.w = ((active_mask_for_e(eg + 3) >> s) & 1ull) ? 1.0f : 0.0f;
            mout[idx] = mv;
        }
    }
}

extern "C" void kernel_launch(void* const* d_in, const int* in_sizes, int n_in,
                              void* d_out, int out_size, void* d_ws, size_t ws_size,
                              hipStream_t stream) {
    const float* x = (const float*)d_in[0];
    float* map_h    = (float*)d_out;
    float* map_mask = (float*)d_out + (size_t)BB * HH * NN * NN;

    // 16384 rows, one per wave: 4096 blocks x 4 waves; mask fused in blocks 0..31
    sppool_fused_kernel<<<BB * HH / 4, 256, 0, stream>>>(x, map_h, map_mask);
}